// Round 3
// baseline (543.669 us; speedup 1.0000x reference)
//
#include <hip/hip_runtime.h>
#include <hip/hip_bf16.h>
#include <hip/hip_cooperative_groups.h>

namespace cg = cooperative_groups;

#define K_ORDER 10
#define NNODES  100000
#define NEDGES  3200000
#define MBLK    1563          // (NNODES+63)/64
#define NPBLK   1024          // persistent blocks: 4 per CU

typedef __bf16 bf16x8 __attribute__((ext_vector_type(8)));
typedef float  floatx4 __attribute__((ext_vector_type(4)));
typedef short  short8v __attribute__((ext_vector_type(8)));

struct WS {
  float* d;        // 11 monomial coefficients
  int*   jmax;     // highest nonzero coefficient index (0 => identity propagation)
  int*   cnt;      // N   degree counts
  int*   off;      // N+1 CSR offsets
  int*   cursor;   // N   scatter cursors
  float* dinv;     // N   deg^-1/2
  int*   csr_col;  // E
  float* csr_w;    // E
  float* h2;       // M x 64 f32 (pre-propagation logits, general path only)
  float* buf0;     // M x 64 f32 (Horner ping)
  float* buf1;     // M x 64 f32 (Horner pong)
  short* w1s;      // W1 bf16 in MFMA-fragment order
  short* w2s;      // W2 bf16 in MFMA-fragment order
  int*   bsum;     // 512 block sums (scan)
  int*   bbase;    // 512 block bases (scan)
};

// Branchless RNE f32->bf16 (bit-identical to __float2bfloat16 for non-NaN,
// which is all we ever feed it). ~3 int VALU ops, no libcall, no branch.
__device__ inline short f2bf(float f) {
  unsigned u = __builtin_bit_cast(unsigned, f);
  u = (u + 0x7fffu + ((u >> 16) & 1u)) >> 16;
  return (short)u;
}

__device__ inline bf16x8 pack8(const float4& lo, const float4& hi) {
  short8v t;
  t[0] = f2bf(lo.x); t[1] = f2bf(lo.y); t[2] = f2bf(lo.z); t[3] = f2bf(lo.w);
  t[4] = f2bf(hi.x); t[5] = f2bf(hi.y); t[6] = f2bf(hi.z); t[7] = f2bf(hi.w);
  return __builtin_bit_cast(bf16x8, t);
}

// ---- weight swizzle body: f32 row-major -> bf16 MFMA B-fragment order ----
// frag (kt, nc): lane l = q*16+m16 holds W[kt*32+q*8+j][nc*16+m16], j=0..7.
__device__ inline void swz_body(const float* __restrict__ W, short* __restrict__ dst,
                                int Kd, int Nd, int t) {
  int lane = t & 63, frag = t >> 6;
  int nfr = Nd >> 4;
  int kt = frag / nfr, nc = frag - kt * nfr;
  int m16 = lane & 15, q = lane >> 4;
  int kbase = kt * 32 + q * 8;
  int col = nc * 16 + m16;
  short v[8];
#pragma unroll
  for (int j = 0; j < 8; ++j) v[j] = f2bf(W[(size_t)(kbase + j) * Nd + col]);
  short4* o = (short4*)&dst[(size_t)t * 8];
  o[0] = make_short4(v[0], v[1], v[2], v[3]);
  o[1] = make_short4(v[4], v[5], v[6], v[7]);
}

// ---- combined: W1 swizzle (blocks 0..63), W2 swizzle (64..71), coeff (72) ----
__global__ __launch_bounds__(256) void k_swzall(const float* __restrict__ W1,
    const float* __restrict__ W2, const float* __restrict__ temp, WS ws) {
  int b = blockIdx.x;
  if (b < 64) {
    swz_body(W1, ws.w1s, 512, 256, b * 256 + threadIdx.x);
  } else if (b < 72) {
    swz_body(W2, ws.w2s, 256, 64, (b - 64) * 256 + threadIdx.x);
  } else if (threadIdx.x == 0) {
    // p(A) = sum_k relu(temp_k)*C(10,k)/1024 * (I+A)^(10-k)(I-A)^k = sum_j d_j A^j
    const double C10[11] = {1,10,45,120,210,252,210,120,45,10,1};
    double dd[11];
    for (int j = 0; j <= K_ORDER; ++j) dd[j] = 0.0;
    for (int k = 0; k <= K_ORDER; ++k) {
      double th = temp[k] > 0.f ? (double)temp[k] : 0.0;
      double c  = th * C10[k] / 1024.0;
      double p[11];
      for (int j = 0; j <= K_ORDER; ++j) p[j] = 0.0;
      p[0] = 1.0;
      int deg = 0;
      for (int i = 0; i < K_ORDER - k; ++i) {   // * (1 + t)
        ++deg;
        for (int j = deg; j >= 1; --j) p[j] += p[j-1];
      }
      for (int i = 0; i < k; ++i) {             // * (1 - t)
        ++deg;
        for (int j = deg; j >= 1; --j) p[j] = p[j] - p[j-1];
      }
      for (int j = 0; j <= K_ORDER; ++j) dd[j] += c * p[j];
    }
    int jm = 0;
    for (int j = 1; j <= K_ORDER; ++j) if (dd[j] != 0.0) jm = j;
    for (int j = 0; j <= K_ORDER; ++j) ws.d[j] = (float)dd[j];
    *ws.jmax = jm;
  }
}

// ---- fused forward: relu(x@W1+b1)@W2+b2, then (jmax==0) log_softmax -> out
//                      else h2 -> ws.h2 for the propagation path.
// PERSISTENT: 1024 blocks (4/CU pinned co-resident; LDS 33.8KB*4=135KB<=160KB,
// __launch_bounds__(256,4) pins <=128 VGPR so 4 waves/SIMD fit). Each block
// grid-strides the 1563 64-row slabs. Per slab: GEMM1 with async 3-buffer
// global_load_lds staging + counted vmcnt(6) + raw s_barrier (never drained
// to 0 inside the K-loop); LDS chunk-XOR swizzle applied on BOTH the global
// source and the ds_read side. Inter-block TLP (16 waves/CU) hides the
// per-phase latency (m97/m114 mechanism).
__global__ __launch_bounds__(256, 4) void k_fwd(const float* __restrict__ A,
    const float* __restrict__ b1, const float* __restrict__ b2,
    WS ws, float* __restrict__ out)
{
  __shared__ __align__(16) char smem[64 * 264 * 2];  // 33792 B; first 24576 B = 3x8KB A bufs in GEMM1
  short* H1s = (short*)smem;
  const int tid = threadIdx.x;
  const int wave = tid >> 6, lane = tid & 63;
  const int q = lane >> 4, m16 = lane & 15;

  // ---- slab-invariant staging geometry ----
  // slot s=(wave*2+j)*64+lane -> (row=s>>3, kg=s&7); LDS slot kg holds global
  // chunk kg^(row&7) (involution). Dest is linear per wave (gload_lds rule).
  const int s0 = wave * 128 + lane, s1 = s0 + 64;
  const int row0 = s0 >> 3, row1 = s1 >> 3;
  const int kgs0 = (s0 & 7) ^ (row0 & 7);
  const int kgs1 = (s1 & 7) ^ (row1 & 7);
  __attribute__((address_space(3))) char* lbase =
      (__attribute__((address_space(3))) char*)smem;
  const unsigned lo0 = (unsigned)(wave * 2) * 1024u;   // wave-uniform LDS offsets
  const unsigned lo1 = lo0 + 1024u;

  // read-side swizzled 16B-chunk offsets (per-lane constants)
  const int rx = m16 & 7;
  const unsigned cs0 = (unsigned)((2 * q) ^ rx) * 16u;
  const unsigned cs1 = (unsigned)((2 * q + 1) ^ rx) * 16u;

  // B fragment base for this wave (cols wave*64..+63); kt stride = 8192 shorts.
  const short* bcol = ws.w1s + ((size_t)(wave * 4) * 64 + lane) * 8;

  // ---- hoisted uniforms (loaded once per block, not per slab) ----
  float bv[4];
#pragma unroll
  for (int c = 0; c < 4; ++c) bv[c] = b1[wave * 64 + c * 16 + m16];
  const int jm = *ws.jmax;
  const float d0 = ws.d[0];
  float bv2[4];
#pragma unroll
  for (int c = 0; c < 4; ++c) bv2[c] = b2[c * 16 + m16];

#define STAGE(KT, BUF) do { \
    __builtin_amdgcn_global_load_lds( \
      (const __attribute__((address_space(1))) void*)(gp0 + (KT) * 32), \
      (__attribute__((address_space(3))) void*)(lbase + (BUF) * 8192 + lo0), 16, 0, 0); \
    __builtin_amdgcn_global_load_lds( \
      (const __attribute__((address_space(1))) void*)(gp1 + (KT) * 32), \
      (__attribute__((address_space(3))) void*)(lbase + (BUF) * 8192 + lo1), 16, 0, 0); \
  } while (0)

#pragma unroll 1
  for (int slab = blockIdx.x; slab < MBLK; slab += NPBLK) {
    const int bm = slab * 64;
    int gr0 = bm + row0; if (gr0 > NNODES - 1) gr0 = NNODES - 1;
    int gr1 = bm + row1; if (gr1 > NNODES - 1) gr1 = NNODES - 1;
    const float* gp0 = A + (size_t)gr0 * 512 + kgs0 * 4;
    const float* gp1 = A + (size_t)gr1 * 512 + kgs1 * 4;

    floatx4 acc[4][4] = {};

    // prologue: stage tiles 0,1; order vs B-loads pinned so vmcnt counts are exact
    STAGE(0, 0);
    STAGE(1, 1);
    asm volatile("" ::: "memory");
    bf16x8 pb[4];
#pragma unroll
    for (int c = 0; c < 4; ++c) pb[c] = *(const bf16x8*)(bcol + c * 512);

#pragma unroll 1
    for (int kt = 0; kt < 16; ++kt) {
      // need STAGE(kt) complete; newer ops = STAGE(kt+1)[2] + BLOAD(kt)[4] = 6
      if (kt < 15) asm volatile("s_waitcnt vmcnt(6)" ::: "memory");
      else         asm volatile("s_waitcnt vmcnt(4)" ::: "memory");
      __builtin_amdgcn_s_barrier();
      asm volatile("" ::: "memory");   // no LDS reads may hoist above the barrier

      if (kt < 14) STAGE(kt + 2, (kt + 2) % 3);   // post-barrier: reuse-dist-3 safe
      bf16x8 pbn[4];
      if (kt < 15) {
        const short* bn = bcol + (size_t)(kt + 1) * 8192;
#pragma unroll
        for (int c = 0; c < 4; ++c) pbn[c] = *(const bf16x8*)(bn + c * 512);
      }

      const char* bufp = (const char*)smem + (kt % 3) * 8192;
      bf16x8 af[4];
#pragma unroll
      for (int r = 0; r < 4; ++r) {
        const char* rp = bufp + (unsigned)(r * 16 + m16) * 128u;
        float4 vlo = *(const float4*)(rp + cs0);
        float4 vhi = *(const float4*)(rp + cs1);
        af[r] = pack8(vlo, vhi);
      }
#pragma unroll
      for (int r = 0; r < 4; ++r)
#pragma unroll
        for (int c = 0; c < 4; ++c)
          acc[r][c] = __builtin_amdgcn_mfma_f32_16x16x32_bf16(af[r], pb[c], acc[r][c], 0, 0, 0);
      if (kt < 15) {
#pragma unroll
        for (int c = 0; c < 4; ++c) pb[c] = pbn[c];
      }
    }

    // Phase B: bias + relu -> H1s bf16 tile (overwrites A-buf alias; all reads done)
    __syncthreads();
#pragma unroll
    for (int r = 0; r < 4; ++r)
#pragma unroll
      for (int c = 0; c < 4; ++c)
#pragma unroll
        for (int reg = 0; reg < 4; ++reg)
          H1s[(r * 16 + q * 4 + reg) * 264 + wave * 64 + c * 16 + m16] =
              f2bf(fmaxf(acc[r][c][reg] + bv[c], 0.f));
    __syncthreads();

    // Phase C: GEMM2 — wave w computes rows w*16..+15, all 64 cols. K=256.
    floatx4 acc2[4] = {};
#pragma unroll
    for (int kt = 0; kt < 8; ++kt) {
      bf16x8 af2 = *(const bf16x8*)&H1s[(wave * 16 + m16) * 264 + kt * 32 + q * 8];
      const short* bb = ws.w2s + ((size_t)(kt * 4) * 64 + lane) * 8;
#pragma unroll
      for (int c = 0; c < 4; ++c) {
        bf16x8 bf2 = *(const bf16x8*)(bb + c * 512);
        acc2[c] = __builtin_amdgcn_mfma_f32_16x16x32_bf16(af2, bf2, acc2[c], 0, 0, 0);
      }
    }
    __syncthreads();   // H1s/A-buf region must be quiescent before next slab's STAGE

    // Phase D: epilogue. row = bm + wave*16 + q*4 + reg, col = c*16 + m16.
    if (jm > 0) {
#pragma unroll
      for (int reg = 0; reg < 4; ++reg) {
        int rowm = bm + wave * 16 + q * 4 + reg;
        if (rowm < NNODES) {
          size_t o = (size_t)rowm * 64 + m16;
#pragma unroll
          for (int c = 0; c < 4; ++c)
            ws.h2[o + c * 16] = acc2[c][reg] + bv2[c];
        }
      }
    } else {
#pragma unroll
      for (int reg = 0; reg < 4; ++reg) {
        float v[4];
#pragma unroll
        for (int c = 0; c < 4; ++c) v[c] = d0 * (acc2[c][reg] + bv2[c]);
        float m = fmaxf(fmaxf(v[0], v[1]), fmaxf(v[2], v[3]));
#pragma unroll
        for (int o = 1; o < 16; o <<= 1) m = fmaxf(m, __shfl_xor(m, o));
        float s = 0.f;
#pragma unroll
        for (int c = 0; c < 4; ++c) s += __expf(v[c] - m);
#pragma unroll
        for (int o = 1; o < 16; o <<= 1) s += __shfl_xor(s, o);
        float ls = __logf(s);
        int rowm = bm + wave * 16 + q * 4 + reg;
        if (rowm < NNODES) {
          size_t o = (size_t)rowm * 64 + m16;
#pragma unroll
          for (int c = 0; c < 4; ++c) out[o + c * 16] = v[c] - m - ls;
        }
      }
    }
  }
#undef STAGE
}

// ---- cooperative graph-propagation path (entirely gated on jmax>0) ----
// 512 blocks x 256 threads. Phases: init/zero -> count -> scan -> scatter ->
// Horner adjacency passes -> log_softmax, with grid.sync() between phases.
__global__ __launch_bounds__(256) void k_graph(const int* __restrict__ ei,
                                               WS ws, float* __restrict__ out) {
  const int jm = *ws.jmax;
  if (jm == 0) return;   // uniform across grid: no sync executed by anyone
  cg::grid_group g = cg::this_grid();
  const int t = threadIdx.x;
  const int gtid = blockIdx.x * 256 + t;
  const int gstride = 512 * 256;

  // phase 1: zero cnt/cursor; init Horner buffer = d[jm] * h2
  for (int i = gtid; i < NNODES; i += gstride) { ws.cnt[i] = 0; ws.cursor[i] = 0; }
  {
    float s = ws.d[jm];
    float* dst = (jm & 1) ? ws.buf1 : ws.buf0;
    for (int i = gtid; i < NNODES * 64; i += gstride) dst[i] = s * ws.h2[i];
  }
  g.sync();

  // phase 2: degree count
  for (int e = gtid; e < NEDGES; e += gstride) atomicAdd(&ws.cnt[ei[e]], 1);
  g.sync();

  // phase 3: per-block inclusive scan of a 256-node chunk
  __shared__ int sd[256];
  const int i3 = blockIdx.x * 256 + t;
  {
    int v = (i3 < NNODES) ? ws.cnt[i3] : 0;
    if (i3 < NNODES) ws.dinv[i3] = v > 0 ? rsqrtf((float)v) : 0.f;
    sd[t] = v;
    __syncthreads();
    for (int o = 1; o < 256; o <<= 1) {
      int a = (t >= o) ? sd[t - o] : 0;
      __syncthreads();
      sd[t] += a;
      __syncthreads();
    }
    if (i3 < NNODES) ws.off[i3 + 1] = sd[t];
    if (t == 255) ws.bsum[blockIdx.x] = sd[255];
    if (blockIdx.x == 0 && t == 0) ws.off[0] = 0;
  }
  g.sync();

  // phase 4: block 0 exclusive-scans the 512 block sums
  if (blockIdx.x == 0) {
    __shared__ int sd2[512];
    sd2[t] = ws.bsum[t]; sd2[t + 256] = ws.bsum[t + 256];
    __syncthreads();
    if (t == 0) {
      int run = 0;
      for (int b = 0; b < 512; ++b) { int x = sd2[b]; sd2[b] = run; run += x; }
    }
    __syncthreads();
    ws.bbase[t] = sd2[t]; ws.bbase[t + 256] = sd2[t + 256];
  }
  g.sync();

  // phase 5: add block bases
  if (i3 < NNODES) ws.off[i3 + 1] += ws.bbase[blockIdx.x];
  g.sync();

  // phase 6: scatter edges into CSR
  for (int e = gtid; e < NEDGES; e += gstride) {
    int row = ei[e], col = ei[NEDGES + e];
    float wv = ws.dinv[row] * ws.dinv[col];
    int pos = ws.off[row] + atomicAdd(&ws.cursor[row], 1);
    ws.csr_col[pos] = col;
    ws.csr_w[pos]   = wv;
  }
  g.sync();

  // phase 7: Horner adjacency passes: dst = A_hat @ src + d_j * h2
  const int lane = t & 63;
  const int wid0 = blockIdx.x * 4 + (t >> 6);
  const int nwaves = 512 * 4;
  for (int j = jm - 1; j >= 0; --j) {
    const float* src = ((j + 1) & 1) ? ws.buf1 : ws.buf0;
    float*       dst = (j & 1)       ? ws.buf1 : ws.buf0;
    float dj = ws.d[j];
    for (int node = wid0; node < NNODES; node += nwaves) {
      int s = ws.off[node], e = ws.off[node + 1];
      float acc = 0.f;
      for (int base = s; base < e; base += 64) {
        int idx = base + lane;
        int cc = 0; float cw = 0.f;
        if (idx < e) { cc = ws.csr_col[idx]; cw = ws.csr_w[idx]; }
        int n = min(64, e - base);
        for (int u = 0; u < n; ++u) {
          int   c2 = __shfl(cc, u);
          float w2 = __shfl(cw, u);
          acc += w2 * src[(size_t)c2 * 64 + lane];
        }
      }
      dst[(size_t)node * 64 + lane] = acc + dj * ws.h2[(size_t)node * 64 + lane];
    }
    g.sync();
  }

  // phase 8: log_softmax over buf0 -> out
  for (int node = wid0; node < NNODES; node += nwaves) {
    size_t idx = (size_t)node * 64 + lane;
    float v = ws.buf0[idx];
    float m = v;
#pragma unroll
    for (int o = 32; o > 0; o >>= 1) m = fmaxf(m, __shfl_xor(m, o));
    float s = __expf(v - m);
#pragma unroll
    for (int o = 32; o > 0; o >>= 1) s += __shfl_xor(s, o);
    out[idx] = (v - m) - __logf(s);
  }
}

// ---------------- host ----------------
extern "C" void kernel_launch(void* const* d_in, const int* in_sizes, int n_in,
                              void* d_out, int out_size, void* d_ws, size_t ws_size,
                              hipStream_t stream) {
  const float* x    = (const float*)d_in[0];
  const int*   ei   = (const int*)  d_in[1];
  const float* W1   = (const float*)d_in[2];
  const float* b1   = (const float*)d_in[3];
  const float* W2   = (const float*)d_in[4];
  const float* b2   = (const float*)d_in[5];
  const float* temp = (const float*)d_in[6];
  float* out = (float*)d_out;

  char* w = (char*)d_ws;
  size_t o = 0;
  auto bump = [&](size_t bytes) { size_t r = o; o += (bytes + 255) & ~(size_t)255; return r; };
  WS ws;
  ws.d       = (float*)(w + bump(11 * 4));
  ws.jmax    = (int*)  (w + bump(4));
  ws.cnt     = (int*)  (w + bump((size_t)NNODES * 4));
  ws.off     = (int*)  (w + bump((size_t)(NNODES + 1) * 4));
  ws.cursor  = (int*)  (w + bump((size_t)NNODES * 4));
  ws.dinv    = (float*)(w + bump((size_t)NNODES * 4));
  ws.csr_col = (int*)  (w + bump((size_t)NEDGES * 4));
  ws.csr_w   = (float*)(w + bump((size_t)NEDGES * 4));
  ws.h2      = (float*)(w + bump((size_t)NNODES * 64 * 4));
  ws.buf0    = (float*)(w + bump((size_t)NNODES * 64 * 4));
  ws.buf1    = (float*)(w + bump((size_t)NNODES * 64 * 4));
  ws.w1s     = (short*)(w + bump((size_t)512 * 256 * 2));
  ws.w2s     = (short*)(w + bump((size_t)256 * 64 * 2));
  ws.bsum    = (int*)  (w + bump(512 * 4));
  ws.bbase   = (int*)  (w + bump(512 * 4));

  k_swzall<<<73, 256, 0, stream>>>(W1, W2, temp, ws);
  k_fwd<<<NPBLK, 256, 0, stream>>>(x, b1, b2, ws, out);

  void* args[] = { (void*)&ei, (void*)&ws, (void*)&out };
  hipLaunchCooperativeKernel((void*)k_graph, dim3(512), dim3(256), args, 0, stream);
}

// Round 4
// 424.729 us; speedup vs baseline: 1.2800x; 1.2800x over previous
//
#include <hip/hip_runtime.h>
#include <hip/hip_bf16.h>
#include <hip/hip_cooperative_groups.h>

namespace cg = cooperative_groups;

#define K_ORDER 10
#define NNODES  100000
#define NEDGES  3200000
#define MBLK    1563          // (NNODES+63)/64
#define NPBLK   768           // persistent blocks: 3 per CU (152 regs/wave -> 3 waves/SIMD)

typedef __bf16 bf16x8 __attribute__((ext_vector_type(8)));
typedef float  floatx4 __attribute__((ext_vector_type(4)));
typedef short  short8v __attribute__((ext_vector_type(8)));

struct WS {
  float* d;        // 11 monomial coefficients
  int*   jmax;     // highest nonzero coefficient index (0 => identity propagation)
  int*   cnt;      // N   degree counts
  int*   off;      // N+1 CSR offsets
  int*   cursor;   // N   scatter cursors
  float* dinv;     // N   deg^-1/2
  int*   csr_col;  // E
  float* csr_w;    // E
  float* h2;       // M x 64 f32 (pre-propagation logits, general path only)
  float* buf0;     // M x 64 f32 (Horner ping)
  float* buf1;     // M x 64 f32 (Horner pong)
  short* w1s;      // W1 bf16 in MFMA-fragment order
  short* w2s;      // W2 bf16 in MFMA-fragment order
  int*   bsum;     // 512 block sums (scan)
  int*   bbase;    // 512 block bases (scan)
};

// Branchless RNE f32->bf16 (bit-identical to __float2bfloat16 for non-NaN,
// which is all we ever feed it). ~3 int VALU ops, no libcall, no branch.
__device__ inline short f2bf(float f) {
  unsigned u = __builtin_bit_cast(unsigned, f);
  u = (u + 0x7fffu + ((u >> 16) & 1u)) >> 16;
  return (short)u;
}

__device__ inline bf16x8 pack8(const float4& lo, const float4& hi) {
  short8v t;
  t[0] = f2bf(lo.x); t[1] = f2bf(lo.y); t[2] = f2bf(lo.z); t[3] = f2bf(lo.w);
  t[4] = f2bf(hi.x); t[5] = f2bf(hi.y); t[6] = f2bf(hi.z); t[7] = f2bf(hi.w);
  return __builtin_bit_cast(bf16x8, t);
}

// ---- weight swizzle body: f32 row-major -> bf16 MFMA B-fragment order ----
// frag (kt, nc): lane l = q*16+m16 holds W[kt*32+q*8+j][nc*16+m16], j=0..7.
__device__ inline void swz_body(const float* __restrict__ W, short* __restrict__ dst,
                                int Kd, int Nd, int t) {
  int lane = t & 63, frag = t >> 6;
  int nfr = Nd >> 4;
  int kt = frag / nfr, nc = frag - kt * nfr;
  int m16 = lane & 15, q = lane >> 4;
  int kbase = kt * 32 + q * 8;
  int col = nc * 16 + m16;
  short v[8];
#pragma unroll
  for (int j = 0; j < 8; ++j) v[j] = f2bf(W[(size_t)(kbase + j) * Nd + col]);
  short4* o = (short4*)&dst[(size_t)t * 8];
  o[0] = make_short4(v[0], v[1], v[2], v[3]);
  o[1] = make_short4(v[4], v[5], v[6], v[7]);
}

// ---- combined: W1 swizzle (blocks 0..63), W2 swizzle (64..71), coeff (72) ----
__global__ __launch_bounds__(256) void k_swzall(const float* __restrict__ W1,
    const float* __restrict__ W2, const float* __restrict__ temp, WS ws) {
  int b = blockIdx.x;
  if (b < 64) {
    swz_body(W1, ws.w1s, 512, 256, b * 256 + threadIdx.x);
  } else if (b < 72) {
    swz_body(W2, ws.w2s, 256, 64, (b - 64) * 256 + threadIdx.x);
  } else if (threadIdx.x == 0) {
    // p(A) = sum_k relu(temp_k)*C(10,k)/1024 * (I+A)^(10-k)(I-A)^k = sum_j d_j A^j
    const double C10[11] = {1,10,45,120,210,252,210,120,45,10,1};
    double dd[11];
    for (int j = 0; j <= K_ORDER; ++j) dd[j] = 0.0;
    for (int k = 0; k <= K_ORDER; ++k) {
      double th = temp[k] > 0.f ? (double)temp[k] : 0.0;
      double c  = th * C10[k] / 1024.0;
      double p[11];
      for (int j = 0; j <= K_ORDER; ++j) p[j] = 0.0;
      p[0] = 1.0;
      int deg = 0;
      for (int i = 0; i < K_ORDER - k; ++i) {   // * (1 + t)
        ++deg;
        for (int j = deg; j >= 1; --j) p[j] += p[j-1];
      }
      for (int i = 0; i < k; ++i) {             // * (1 - t)
        ++deg;
        for (int j = deg; j >= 1; --j) p[j] = p[j] - p[j-1];
      }
      for (int j = 0; j <= K_ORDER; ++j) dd[j] += c * p[j];
    }
    int jm = 0;
    for (int j = 1; j <= K_ORDER; ++j) if (dd[j] != 0.0) jm = j;
    for (int j = 0; j <= K_ORDER; ++j) ws.d[j] = (float)dd[j];
    *ws.jmax = jm;
  }
}

// ---- fused forward: relu(x@W1+b1)@W2+b2, then (jmax==0) log_softmax -> out
//                      else h2 -> ws.h2 for the propagation path.
// PERSISTENT: 768 blocks = 3/CU pinned co-resident. Body needs ~88 arch VGPR
// + 64 AGPR (acc) = ~152 unified regs -> 3 waves/SIMD is the max spill-free
// occupancy; __launch_bounds__(256,3) caps alloc at 170 (r3's (256,4)=128 cap
// caused 381MB of scratch spill traffic). LDS 33.8KB*3=101KB<=160KB.
// Per slab: GEMM1 with async 3-buffer global_load_lds staging + counted
// vmcnt(6) + raw s_barrier (never drained to 0 inside the K-loop); LDS
// chunk-XOR swizzle on BOTH global source and ds_read side. Next slab's first
// two STAGEs issue right after the post-GEMM2 barrier so their HBM latency
// hides under the epilogue (they are the OLDEST queue entries, so the
// existing vmcnt counts still cover them).
__global__ __launch_bounds__(256, 3) void k_fwd(const float* __restrict__ A,
    const float* __restrict__ b1, const float* __restrict__ b2,
    WS ws, float* __restrict__ out)
{
  __shared__ __align__(16) char smem[64 * 264 * 2];  // 33792 B; first 24576 B = 3x8KB A bufs in GEMM1
  short* H1s = (short*)smem;
  const int tid = threadIdx.x;
  const int wave = tid >> 6, lane = tid & 63;
  const int q = lane >> 4, m16 = lane & 15;

  // ---- slab-invariant staging geometry ----
  // slot s=(wave*2+j)*64+lane -> (row=s>>3, kg=s&7); LDS slot kg holds global
  // chunk kg^(row&7) (involution). Dest is linear per wave (gload_lds rule).
  const int s0 = wave * 128 + lane, s1 = s0 + 64;
  const int row0 = s0 >> 3, row1 = s1 >> 3;
  const int kgs0 = (s0 & 7) ^ (row0 & 7);
  const int kgs1 = (s1 & 7) ^ (row1 & 7);
  __attribute__((address_space(3))) char* lbase =
      (__attribute__((address_space(3))) char*)smem;
  const unsigned lo0 = (unsigned)(wave * 2) * 1024u;   // wave-uniform LDS offsets
  const unsigned lo1 = lo0 + 1024u;

  // read-side swizzled 16B-chunk offsets (per-lane constants)
  const int rx = m16 & 7;
  const unsigned cs0 = (unsigned)((2 * q) ^ rx) * 16u;
  const unsigned cs1 = (unsigned)((2 * q + 1) ^ rx) * 16u;

  // B fragment base for this wave (cols wave*64..+63); kt stride = 8192 shorts.
  const short* bcol = ws.w1s + ((size_t)(wave * 4) * 64 + lane) * 8;

  // ---- hoisted uniforms (loaded once per block, not per slab) ----
  float bv[4];
#pragma unroll
  for (int c = 0; c < 4; ++c) bv[c] = b1[wave * 64 + c * 16 + m16];
  const int jm = *ws.jmax;
  const float d0 = ws.d[0];
  float bv2[4];
#pragma unroll
  for (int c = 0; c < 4; ++c) bv2[c] = b2[c * 16 + m16];

#define STAGE(KT, BUF) do { \
    __builtin_amdgcn_global_load_lds( \
      (const __attribute__((address_space(1))) void*)(gp0 + (KT) * 32), \
      (__attribute__((address_space(3))) void*)(lbase + (BUF) * 8192 + lo0), 16, 0, 0); \
    __builtin_amdgcn_global_load_lds( \
      (const __attribute__((address_space(1))) void*)(gp1 + (KT) * 32), \
      (__attribute__((address_space(3))) void*)(lbase + (BUF) * 8192 + lo1), 16, 0, 0); \
  } while (0)

  // pointers for the CURRENT slab (loop-carried; next slab's stage issues early)
  int slab = blockIdx.x;
  auto mkptr = [&](int bm, int rowofs, int kgs) -> const float* {
    int gr = bm + rowofs; if (gr > NNODES - 1) gr = NNODES - 1;
    return A + (size_t)gr * 512 + kgs * 4;
  };
  const float* gp0 = mkptr(slab * 64, row0, kgs0);
  const float* gp1 = mkptr(slab * 64, row1, kgs1);
  if (slab < MBLK) {
    STAGE(0, 0);
    STAGE(1, 1);
  }

#pragma unroll 1
  while (slab < MBLK) {
    const int bm = slab * 64;

    floatx4 acc[4][4] = {};

    asm volatile("" ::: "memory");   // pin STAGE-before-B ordering for vmcnt counts
    bf16x8 pb[4];
#pragma unroll
    for (int c = 0; c < 4; ++c) pb[c] = *(const bf16x8*)(bcol + c * 512);

#pragma unroll 1
    for (int kt = 0; kt < 16; ++kt) {
      // need STAGE(kt) complete; newer ops <= STAGE(kt+1)[2] + BLOAD(kt)[4] = 6
      if (kt < 15) asm volatile("s_waitcnt vmcnt(6)" ::: "memory");
      else         asm volatile("s_waitcnt vmcnt(4)" ::: "memory");
      __builtin_amdgcn_s_barrier();
      asm volatile("" ::: "memory");   // no LDS reads may hoist above the barrier

      if (kt < 14) STAGE(kt + 2, (kt + 2) % 3);   // post-barrier: reuse-dist-3 safe
      bf16x8 pbn[4];
      if (kt < 15) {
        const short* bn = bcol + (size_t)(kt + 1) * 8192;
#pragma unroll
        for (int c = 0; c < 4; ++c) pbn[c] = *(const bf16x8*)(bn + c * 512);
      }

      const char* bufp = (const char*)smem + (kt % 3) * 8192;
      bf16x8 af[4];
#pragma unroll
      for (int r = 0; r < 4; ++r) {
        const char* rp = bufp + (unsigned)(r * 16 + m16) * 128u;
        float4 vlo = *(const float4*)(rp + cs0);
        float4 vhi = *(const float4*)(rp + cs1);
        af[r] = pack8(vlo, vhi);
      }
#pragma unroll
      for (int r = 0; r < 4; ++r)
#pragma unroll
        for (int c = 0; c < 4; ++c)
          acc[r][c] = __builtin_amdgcn_mfma_f32_16x16x32_bf16(af[r], pb[c], acc[r][c], 0, 0, 0);
      if (kt < 15) {
#pragma unroll
        for (int c = 0; c < 4; ++c) pb[c] = pbn[c];
      }
    }

    // Phase B: bias + relu -> H1s bf16 tile (overwrites A-buf alias; all
    // STAGEs completed by the kt=15 vmcnt(4), all reads done at barrier)
    __syncthreads();
#pragma unroll
    for (int r = 0; r < 4; ++r)
#pragma unroll
      for (int c = 0; c < 4; ++c)
#pragma unroll
        for (int reg = 0; reg < 4; ++reg)
          H1s[(r * 16 + q * 4 + reg) * 264 + wave * 64 + c * 16 + m16] =
              f2bf(fmaxf(acc[r][c][reg] + bv[c], 0.f));
    __syncthreads();

    // Phase C: GEMM2 — wave w computes rows w*16..+15, all 64 cols. K=256.
    floatx4 acc2[4] = {};
#pragma unroll
    for (int kt = 0; kt < 8; ++kt) {
      bf16x8 af2 = *(const bf16x8*)&H1s[(wave * 16 + m16) * 264 + kt * 32 + q * 8];
      const short* bb = ws.w2s + ((size_t)(kt * 4) * 64 + lane) * 8;
#pragma unroll
      for (int c = 0; c < 4; ++c) {
        bf16x8 bf2 = *(const bf16x8*)(bb + c * 512);
        acc2[c] = __builtin_amdgcn_mfma_f32_16x16x32_bf16(af2, bf2, acc2[c], 0, 0, 0);
      }
    }
    __syncthreads();   // all H1s/A-buf reads quiescent before next slab's STAGE lands

    // Early-issue next slab's first two STAGEs: HBM latency hides under the
    // epilogue. They are the oldest vmem queue entries at the next slab's
    // kt=0 vmcnt(6), so the wait still covers them.
    const int nslab = slab + NPBLK;
    if (nslab < MBLK) {
      gp0 = mkptr(nslab * 64, row0, kgs0);
      gp1 = mkptr(nslab * 64, row1, kgs1);
      STAGE(0, 0);
      STAGE(1, 1);
    }

    // Phase D: epilogue. row = bm + wave*16 + q*4 + reg, col = c*16 + m16.
    if (jm > 0) {
#pragma unroll
      for (int reg = 0; reg < 4; ++reg) {
        int rowm = bm + wave * 16 + q * 4 + reg;
        if (rowm < NNODES) {
          size_t o = (size_t)rowm * 64 + m16;
#pragma unroll
          for (int c = 0; c < 4; ++c)
            ws.h2[o + c * 16] = acc2[c][reg] + bv2[c];
        }
      }
    } else {
#pragma unroll
      for (int reg = 0; reg < 4; ++reg) {
        float v[4];
#pragma unroll
        for (int c = 0; c < 4; ++c) v[c] = d0 * (acc2[c][reg] + bv2[c]);
        float m = fmaxf(fmaxf(v[0], v[1]), fmaxf(v[2], v[3]));
#pragma unroll
        for (int o = 1; o < 16; o <<= 1) m = fmaxf(m, __shfl_xor(m, o));
        float s = 0.f;
#pragma unroll
        for (int c = 0; c < 4; ++c) s += __expf(v[c] - m);
#pragma unroll
        for (int o = 1; o < 16; o <<= 1) s += __shfl_xor(s, o);
        float ls = __logf(s);
        int rowm = bm + wave * 16 + q * 4 + reg;
        if (rowm < NNODES) {
          size_t o = (size_t)rowm * 64 + m16;
#pragma unroll
          for (int c = 0; c < 4; ++c) out[o + c * 16] = v[c] - m - ls;
        }
      }
    }
    slab = nslab;
  }
#undef STAGE
}

// ---- cooperative graph-propagation path (entirely gated on jmax>0) ----
// 512 blocks x 256 threads. Phases: init/zero -> count -> scan -> scatter ->
// Horner adjacency passes -> log_softmax, with grid.sync() between phases.
__global__ __launch_bounds__(256) void k_graph(const int* __restrict__ ei,
                                               WS ws, float* __restrict__ out) {
  const int jm = *ws.jmax;
  if (jm == 0) return;   // uniform across grid: no sync executed by anyone
  cg::grid_group g = cg::this_grid();
  const int t = threadIdx.x;
  const int gtid = blockIdx.x * 256 + t;
  const int gstride = 512 * 256;

  // phase 1: zero cnt/cursor; init Horner buffer = d[jm] * h2
  for (int i = gtid; i < NNODES; i += gstride) { ws.cnt[i] = 0; ws.cursor[i] = 0; }
  {
    float s = ws.d[jm];
    float* dst = (jm & 1) ? ws.buf1 : ws.buf0;
    for (int i = gtid; i < NNODES * 64; i += gstride) dst[i] = s * ws.h2[i];
  }
  g.sync();

  // phase 2: degree count
  for (int e = gtid; e < NEDGES; e += gstride) atomicAdd(&ws.cnt[ei[e]], 1);
  g.sync();

  // phase 3: per-block inclusive scan of a 256-node chunk
  __shared__ int sd[256];
  const int i3 = blockIdx.x * 256 + t;
  {
    int v = (i3 < NNODES) ? ws.cnt[i3] : 0;
    if (i3 < NNODES) ws.dinv[i3] = v > 0 ? rsqrtf((float)v) : 0.f;
    sd[t] = v;
    __syncthreads();
    for (int o = 1; o < 256; o <<= 1) {
      int a = (t >= o) ? sd[t - o] : 0;
      __syncthreads();
      sd[t] += a;
      __syncthreads();
    }
    if (i3 < NNODES) ws.off[i3 + 1] = sd[t];
    if (t == 255) ws.bsum[blockIdx.x] = sd[255];
    if (blockIdx.x == 0 && t == 0) ws.off[0] = 0;
  }
  g.sync();

  // phase 4: block 0 exclusive-scans the 512 block sums
  if (blockIdx.x == 0) {
    __shared__ int sd2[512];
    sd2[t] = ws.bsum[t]; sd2[t + 256] = ws.bsum[t + 256];
    __syncthreads();
    if (t == 0) {
      int run = 0;
      for (int b = 0; b < 512; ++b) { int x = sd2[b]; sd2[b] = run; run += x; }
    }
    __syncthreads();
    ws.bbase[t] = sd2[t]; ws.bbase[t + 256] = sd2[t + 256];
  }
  g.sync();

  // phase 5: add block bases
  if (i3 < NNODES) ws.off[i3 + 1] += ws.bbase[blockIdx.x];
  g.sync();

  // phase 6: scatter edges into CSR
  for (int e = gtid; e < NEDGES; e += gstride) {
    int row = ei[e], col = ei[NEDGES + e];
    float wv = ws.dinv[row] * ws.dinv[col];
    int pos = ws.off[row] + atomicAdd(&ws.cursor[row], 1);
    ws.csr_col[pos] = col;
    ws.csr_w[pos]   = wv;
  }
  g.sync();

  // phase 7: Horner adjacency passes: dst = A_hat @ src + d_j * h2
  const int lane = t & 63;
  const int wid0 = blockIdx.x * 4 + (t >> 6);
  const int nwaves = 512 * 4;
  for (int j = jm - 1; j >= 0; --j) {
    const float* src = ((j + 1) & 1) ? ws.buf1 : ws.buf0;
    float*       dst = (j & 1)       ? ws.buf1 : ws.buf0;
    float dj = ws.d[j];
    for (int node = wid0; node < NNODES; node += nwaves) {
      int s = ws.off[node], e = ws.off[node + 1];
      float acc = 0.f;
      for (int base = s; base < e; base += 64) {
        int idx = base + lane;
        int cc = 0; float cw = 0.f;
        if (idx < e) { cc = ws.csr_col[idx]; cw = ws.csr_w[idx]; }
        int n = min(64, e - base);
        for (int u = 0; u < n; ++u) {
          int   c2 = __shfl(cc, u);
          float w2 = __shfl(cw, u);
          acc += w2 * src[(size_t)c2 * 64 + lane];
        }
      }
      dst[(size_t)node * 64 + lane] = acc + dj * ws.h2[(size_t)node * 64 + lane];
    }
    g.sync();
  }

  // phase 8: log_softmax over buf0 -> out
  for (int node = wid0; node < NNODES; node += nwaves) {
    size_t idx = (size_t)node * 64 + lane;
    float v = ws.buf0[idx];
    float m = v;
#pragma unroll
    for (int o = 32; o > 0; o >>= 1) m = fmaxf(m, __shfl_xor(m, o));
    float s = __expf(v - m);
#pragma unroll
    for (int o = 32; o > 0; o >>= 1) s += __shfl_xor(s, o);
    out[idx] = (v - m) - __logf(s);
  }
}

// ---------------- host ----------------
extern "C" void kernel_launch(void* const* d_in, const int* in_sizes, int n_in,
                              void* d_out, int out_size, void* d_ws, size_t ws_size,
                              hipStream_t stream) {
  const float* x    = (const float*)d_in[0];
  const int*   ei   = (const int*)  d_in[1];
  const float* W1   = (const float*)d_in[2];
  const float* b1   = (const float*)d_in[3];
  const float* W2   = (const float*)d_in[4];
  const float* b2   = (const float*)d_in[5];
  const float* temp = (const float*)d_in[6];
  float* out = (float*)d_out;

  char* w = (char*)d_ws;
  size_t o = 0;
  auto bump = [&](size_t bytes) { size_t r = o; o += (bytes + 255) & ~(size_t)255; return r; };
  WS ws;
  ws.d       = (float*)(w + bump(11 * 4));
  ws.jmax    = (int*)  (w + bump(4));
  ws.cnt     = (int*)  (w + bump((size_t)NNODES * 4));
  ws.off     = (int*)  (w + bump((size_t)(NNODES + 1) * 4));
  ws.cursor  = (int*)  (w + bump((size_t)NNODES * 4));
  ws.dinv    = (float*)(w + bump((size_t)NNODES * 4));
  ws.csr_col = (int*)  (w + bump((size_t)NEDGES * 4));
  ws.csr_w   = (float*)(w + bump((size_t)NEDGES * 4));
  ws.h2      = (float*)(w + bump((size_t)NNODES * 64 * 4));
  ws.buf0    = (float*)(w + bump((size_t)NNODES * 64 * 4));
  ws.buf1    = (float*)(w + bump((size_t)NNODES * 64 * 4));
  ws.w1s     = (short*)(w + bump((size_t)512 * 256 * 2));
  ws.w2s     = (short*)(w + bump((size_t)256 * 64 * 2));
  ws.bsum    = (int*)  (w + bump(512 * 4));
  ws.bbase   = (int*)  (w + bump(512 * 4));

  k_swzall<<<73, 256, 0, stream>>>(W1, W2, temp, ws);
  k_fwd<<<NPBLK, 256, 0, stream>>>(x, b1, b2, ws, out);

  void* args[] = { (void*)&ei, (void*)&ws, (void*)&out };
  hipLaunchCooperativeKernel((void*)k_graph, dim3(512), dim3(256), args, 0, stream);
}

// Round 5
// 406.567 us; speedup vs baseline: 1.3372x; 1.0447x over previous
//
#include <hip/hip_runtime.h>
#include <hip/hip_bf16.h>
#include <hip/hip_cooperative_groups.h>

namespace cg = cooperative_groups;

#define K_ORDER 10
#define NNODES  100000
#define NEDGES  3200000
#define MBLK    1563          // (NNODES+63)/64

typedef __bf16 bf16x8 __attribute__((ext_vector_type(8)));
typedef float  floatx4 __attribute__((ext_vector_type(4)));
typedef short  short8v __attribute__((ext_vector_type(8)));

struct WS {
  float* d;        // 11 monomial coefficients
  int*   jmax;     // highest nonzero coefficient index (0 => identity propagation)
  int*   cnt;      // N   degree counts
  int*   off;      // N+1 CSR offsets
  int*   cursor;   // N   scatter cursors
  float* dinv;     // N   deg^-1/2
  int*   csr_col;  // E
  float* csr_w;    // E
  float* h2;       // M x 64 f32 (pre-propagation logits, general path only)
  float* buf0;     // M x 64 f32 (Horner ping)
  float* buf1;     // M x 64 f32 (Horner pong)
  short* w1s;      // W1 bf16 in MFMA-fragment order
  short* w2s;      // W2 bf16 in MFMA-fragment order
  int*   bsum;     // 512 block sums (scan)
  int*   bbase;    // 512 block bases (scan)
};

// Branchless RNE f32->bf16 (bit-identical to __float2bfloat16 for non-NaN,
// which is all we ever feed it).
__device__ inline short f2bf(float f) {
  unsigned u = __builtin_bit_cast(unsigned, f);
  u = (u + 0x7fffu + ((u >> 16) & 1u)) >> 16;
  return (short)u;
}

__device__ inline bf16x8 pack8(const float4& lo, const float4& hi) {
  short8v t;
  t[0] = f2bf(lo.x); t[1] = f2bf(lo.y); t[2] = f2bf(lo.z); t[3] = f2bf(lo.w);
  t[4] = f2bf(hi.x); t[5] = f2bf(hi.y); t[6] = f2bf(hi.z); t[7] = f2bf(hi.w);
  return __builtin_bit_cast(bf16x8, t);
}

// ---- weight swizzle body: f32 row-major -> bf16 MFMA B-fragment order ----
// frag (kt, nc): lane l = q*16+m16 holds W[kt*32+q*8+j][nc*16+m16], j=0..7.
__device__ inline void swz_body(const float* __restrict__ W, short* __restrict__ dst,
                                int Kd, int Nd, int t) {
  int lane = t & 63, frag = t >> 6;
  int nfr = Nd >> 4;
  int kt = frag / nfr, nc = frag - kt * nfr;
  int m16 = lane & 15, q = lane >> 4;
  int kbase = kt * 32 + q * 8;
  int col = nc * 16 + m16;
  short v[8];
#pragma unroll
  for (int j = 0; j < 8; ++j) v[j] = f2bf(W[(size_t)(kbase + j) * Nd + col]);
  short4* o = (short4*)&dst[(size_t)t * 8];
  o[0] = make_short4(v[0], v[1], v[2], v[3]);
  o[1] = make_short4(v[4], v[5], v[6], v[7]);
}

// ---- combined: W1 swizzle (blocks 0..63), W2 swizzle (64..71), coeff (72) ----
__global__ __launch_bounds__(256) void k_swzall(const float* __restrict__ W1,
    const float* __restrict__ W2, const float* __restrict__ temp, WS ws) {
  int b = blockIdx.x;
  if (b < 64) {
    swz_body(W1, ws.w1s, 512, 256, b * 256 + threadIdx.x);
  } else if (b < 72) {
    swz_body(W2, ws.w2s, 256, 64, (b - 64) * 256 + threadIdx.x);
  } else if (threadIdx.x == 0) {
    // p(A) = sum_k relu(temp_k)*C(10,k)/1024 * (I+A)^(10-k)(I-A)^k = sum_j d_j A^j
    const double C10[11] = {1,10,45,120,210,252,210,120,45,10,1};
    double dd[11];
    for (int j = 0; j <= K_ORDER; ++j) dd[j] = 0.0;
    for (int k = 0; k <= K_ORDER; ++k) {
      double th = temp[k] > 0.f ? (double)temp[k] : 0.0;
      double c  = th * C10[k] / 1024.0;
      double p[11];
      for (int j = 0; j <= K_ORDER; ++j) p[j] = 0.0;
      p[0] = 1.0;
      int deg = 0;
      for (int i = 0; i < K_ORDER - k; ++i) {   // * (1 + t)
        ++deg;
        for (int j = deg; j >= 1; --j) p[j] += p[j-1];
      }
      for (int i = 0; i < k; ++i) {             // * (1 - t)
        ++deg;
        for (int j = deg; j >= 1; --j) p[j] = p[j] - p[j-1];
      }
      for (int j = 0; j <= K_ORDER; ++j) dd[j] += c * p[j];
    }
    int jm = 0;
    for (int j = 1; j <= K_ORDER; ++j) if (dd[j] != 0.0) jm = j;
    for (int j = 0; j <= K_ORDER; ++j) ws.d[j] = (float)dd[j];
    *ws.jmax = jm;
  }
}

// ---- fused forward: relu(x@W1+b1)@W2+b2, then (jmax==0) log_softmax -> out
//                      else h2 -> ws.h2 for the propagation path.
// One block per 64-row slab (1563 blocks, non-persistent — the best-measured
// base, r2). GEMM1: A tile (64x32 f32, 8KB) staged into LDS via
// global_load_lds, FOUR-buffered and staged THREE K-steps ahead (~2100cy
// lead vs ~900cy HBM latency), counted vmcnt(12/10/4) + raw s_barrier
// (never drained to 0 in-loop). W1 B-fragments prefetched TWO K-steps ahead
// (~1400cy lead vs ~300cy L2 latency) so the compiler's pre-MFMA vmcnt is a
// no-op. LDS chunk-XOR swizzle applied on BOTH the per-lane global source
// address and the ds_read address. GEMM2's first B-fragments issue right
// after GEMM1 so they fly during Phase B; GEMM2 B is 1-deep prefetched.
__global__ __launch_bounds__(256) void k_fwd(const float* __restrict__ A,
    const float* __restrict__ b1, const float* __restrict__ b2,
    WS ws, float* __restrict__ out)
{
  __shared__ __align__(16) char smem[64 * 264 * 2];  // 33792 B; first 32768 B = 4x8KB A bufs in GEMM1
  short* H1s = (short*)smem;
  const int tid = threadIdx.x;
  const int wave = tid >> 6, lane = tid & 63;
  const int q = lane >> 4, m16 = lane & 15;
  const int bm = blockIdx.x * 64;

  // ---- staging map: slot s=(wave*2+j)*64+lane -> (row=s>>3, kg=s&7); the LDS
  // slot kg holds global chunk kg^(row&7) (involution). Dest is linear per wave.
  const int s0 = wave * 128 + lane, s1 = s0 + 64;
  const int row0 = s0 >> 3, row1 = s1 >> 3;
  const int kgs0 = (s0 & 7) ^ (row0 & 7);
  const int kgs1 = (s1 & 7) ^ (row1 & 7);
  int gr0 = bm + row0; if (gr0 > NNODES - 1) gr0 = NNODES - 1;
  int gr1 = bm + row1; if (gr1 > NNODES - 1) gr1 = NNODES - 1;
  const float* gp0 = A + (size_t)gr0 * 512 + kgs0 * 4;
  const float* gp1 = A + (size_t)gr1 * 512 + kgs1 * 4;
  __attribute__((address_space(3))) char* lbase =
      (__attribute__((address_space(3))) char*)smem;
  const unsigned lo0 = (unsigned)(wave * 2) * 1024u;   // wave-uniform LDS offsets
  const unsigned lo1 = lo0 + 1024u;

  // read-side swizzled 16B-chunk offsets (per-lane constants)
  const int rx = m16 & 7;
  const unsigned cs0 = (unsigned)((2 * q) ^ rx) * 16u;
  const unsigned cs1 = (unsigned)((2 * q + 1) ^ rx) * 16u;

  // B fragment base for this wave (cols wave*64..+63); kt stride = 8192 shorts.
  const short* bcol = ws.w1s + ((size_t)(wave * 4) * 64 + lane) * 8;

#define STAGE(KT, BUF) do { \
    __builtin_amdgcn_global_load_lds( \
      (const __attribute__((address_space(1))) void*)(gp0 + (KT) * 32), \
      (__attribute__((address_space(3))) void*)(lbase + (BUF) * 8192 + lo0), 16, 0, 0); \
    __builtin_amdgcn_global_load_lds( \
      (const __attribute__((address_space(1))) void*)(gp1 + (KT) * 32), \
      (__attribute__((address_space(3))) void*)(lbase + (BUF) * 8192 + lo1), 16, 0, 0); \
  } while (0)

  floatx4 acc[4][4] = {};

  // prologue: stage tiles 0,1,2 (order pinned before B loads so vmcnt counts hold)
  STAGE(0, 0);
  STAGE(1, 1);
  STAGE(2, 2);
  asm volatile("" ::: "memory");
  bf16x8 pb[4], pbn[4];
#pragma unroll
  for (int c = 0; c < 4; ++c) pb[c]  = *(const bf16x8*)(bcol + c * 512);
#pragma unroll
  for (int c = 0; c < 4; ++c) pbn[c] = *(const bf16x8*)(bcol + 8192 + c * 512);

#pragma unroll 1
  for (int kt = 0; kt < 16; ++kt) {
    // need STAGE(kt) landed. Outstanding-allowed (newest) ops:
    //  kt<=13: STAGE(kt+1,kt+2){4} + B(kt),B(kt+1){8}  -> vmcnt(12)
    //  kt==14: STAGE(15){2} + B(14),B(15){8}           -> vmcnt(10)
    //  kt==15: B(15){4}                                -> vmcnt(4)
    if (kt <= 13)      asm volatile("s_waitcnt vmcnt(12)" ::: "memory");
    else if (kt == 14) asm volatile("s_waitcnt vmcnt(10)" ::: "memory");
    else               asm volatile("s_waitcnt vmcnt(4)"  ::: "memory");
    __builtin_amdgcn_s_barrier();
    asm volatile("" ::: "memory");   // no LDS reads may hoist above the barrier

    if (kt <= 12) STAGE(kt + 3, (kt + 3) & 3);   // post-barrier: reuse-dist-4 safe
    asm volatile("" ::: "memory");   // STAGE precedes this body's B loads

    bf16x8 pbn2[4];
    if (kt <= 13) {
      const short* bn = bcol + (size_t)(kt + 2) * 8192;
#pragma unroll
      for (int c = 0; c < 4; ++c) pbn2[c] = *(const bf16x8*)(bn + c * 512);
    }

    const char* bufp = (const char*)smem + (kt & 3) * 8192;
    bf16x8 af[4];
#pragma unroll
    for (int r = 0; r < 4; ++r) {
      const char* rp = bufp + (unsigned)(r * 16 + m16) * 128u;
      float4 vlo = *(const float4*)(rp + cs0);
      float4 vhi = *(const float4*)(rp + cs1);
      af[r] = pack8(vlo, vhi);
    }
#pragma unroll
    for (int r = 0; r < 4; ++r)
#pragma unroll
      for (int c = 0; c < 4; ++c)
        acc[r][c] = __builtin_amdgcn_mfma_f32_16x16x32_bf16(af[r], pb[c], acc[r][c], 0, 0, 0);

    if (kt <= 14) {
#pragma unroll
      for (int c = 0; c < 4; ++c) pb[c] = pbn[c];
    }
    if (kt <= 13) {
#pragma unroll
      for (int c = 0; c < 4; ++c) pbn[c] = pbn2[c];
    }
  }
#undef STAGE

  // Early-issue GEMM2's first B fragments: they fly during Phase B.
  bf16x8 g2b[4];
  {
    const short* bb0 = ws.w2s + (size_t)lane * 8;
#pragma unroll
    for (int c = 0; c < 4; ++c) g2b[c] = *(const bf16x8*)(bb0 + c * 512);
  }

  // Phase B: bias + relu -> H1s bf16 tile (overwrites A-buf alias).
  float bv[4];
#pragma unroll
  for (int c = 0; c < 4; ++c) bv[c] = b1[wave * 64 + c * 16 + m16];
  __syncthreads();   // all waves' GEMM1 LDS reads landed before H1s overwrite
#pragma unroll
  for (int r = 0; r < 4; ++r)
#pragma unroll
    for (int c = 0; c < 4; ++c)
#pragma unroll
      for (int reg = 0; reg < 4; ++reg)
        H1s[(r * 16 + q * 4 + reg) * 264 + wave * 64 + c * 16 + m16] =
            f2bf(fmaxf(acc[r][c][reg] + bv[c], 0.f));
  __syncthreads();

  // Phase C: GEMM2 — wave w computes rows w*16..+15, all 64 cols. K=256.
  // B2 1-deep prefetched.
  floatx4 acc2[4] = {};
#pragma unroll
  for (int kt = 0; kt < 8; ++kt) {
    bf16x8 g2bn[4];
    if (kt < 7) {
      const short* bb = ws.w2s + ((size_t)((kt + 1) * 4) * 64 + lane) * 8;
#pragma unroll
      for (int c = 0; c < 4; ++c) g2bn[c] = *(const bf16x8*)(bb + c * 512);
    }
    bf16x8 af2 = *(const bf16x8*)&H1s[(wave * 16 + m16) * 264 + kt * 32 + q * 8];
#pragma unroll
    for (int c = 0; c < 4; ++c)
      acc2[c] = __builtin_amdgcn_mfma_f32_16x16x32_bf16(af2, g2b[c], acc2[c], 0, 0, 0);
    if (kt < 7) {
#pragma unroll
      for (int c = 0; c < 4; ++c) g2b[c] = g2bn[c];
    }
  }

  // Phase D: epilogue. row = bm + wave*16 + q*4 + reg, col = c*16 + m16.
  int jm = *ws.jmax;
  float d0 = ws.d[0];
  float bv2[4];
#pragma unroll
  for (int c = 0; c < 4; ++c) bv2[c] = b2[c * 16 + m16];

  if (jm > 0) {
#pragma unroll
    for (int reg = 0; reg < 4; ++reg) {
      int rowm = bm + wave * 16 + q * 4 + reg;
      if (rowm < NNODES) {
        size_t o = (size_t)rowm * 64 + m16;
#pragma unroll
        for (int c = 0; c < 4; ++c)
          ws.h2[o + c * 16] = acc2[c][reg] + bv2[c];
      }
    }
  } else {
#pragma unroll
    for (int reg = 0; reg < 4; ++reg) {
      float v[4];
#pragma unroll
      for (int c = 0; c < 4; ++c) v[c] = d0 * (acc2[c][reg] + bv2[c]);
      float m = fmaxf(fmaxf(v[0], v[1]), fmaxf(v[2], v[3]));
#pragma unroll
      for (int o = 1; o < 16; o <<= 1) m = fmaxf(m, __shfl_xor(m, o));
      float s = 0.f;
#pragma unroll
      for (int c = 0; c < 4; ++c) s += __expf(v[c] - m);
#pragma unroll
      for (int o = 1; o < 16; o <<= 1) s += __shfl_xor(s, o);
      float ls = __logf(s);
      int rowm = bm + wave * 16 + q * 4 + reg;
      if (rowm < NNODES) {
        size_t o = (size_t)rowm * 64 + m16;
#pragma unroll
        for (int c = 0; c < 4; ++c) out[o + c * 16] = v[c] - m - ls;
      }
    }
  }
}

// ---- cooperative graph-propagation path (entirely gated on jmax>0) ----
// 512 blocks x 256 threads. Phases: init/zero -> count -> scan -> scatter ->
// Horner adjacency passes -> log_softmax, with grid.sync() between phases.
__global__ __launch_bounds__(256) void k_graph(const int* __restrict__ ei,
                                               WS ws, float* __restrict__ out) {
  const int jm = *ws.jmax;
  if (jm == 0) return;   // uniform across grid: no sync executed by anyone
  cg::grid_group g = cg::this_grid();
  const int t = threadIdx.x;
  const int gtid = blockIdx.x * 256 + t;
  const int gstride = 512 * 256;

  // phase 1: zero cnt/cursor; init Horner buffer = d[jm] * h2
  for (int i = gtid; i < NNODES; i += gstride) { ws.cnt[i] = 0; ws.cursor[i] = 0; }
  {
    float s = ws.d[jm];
    float* dst = (jm & 1) ? ws.buf1 : ws.buf0;
    for (int i = gtid; i < NNODES * 64; i += gstride) dst[i] = s * ws.h2[i];
  }
  g.sync();

  // phase 2: degree count
  for (int e = gtid; e < NEDGES; e += gstride) atomicAdd(&ws.cnt[ei[e]], 1);
  g.sync();

  // phase 3: per-block inclusive scan of a 256-node chunk
  __shared__ int sd[256];
  const int i3 = blockIdx.x * 256 + t;
  {
    int v = (i3 < NNODES) ? ws.cnt[i3] : 0;
    if (i3 < NNODES) ws.dinv[i3] = v > 0 ? rsqrtf((float)v) : 0.f;
    sd[t] = v;
    __syncthreads();
    for (int o = 1; o < 256; o <<= 1) {
      int a = (t >= o) ? sd[t - o] : 0;
      __syncthreads();
      sd[t] += a;
      __syncthreads();
    }
    if (i3 < NNODES) ws.off[i3 + 1] = sd[t];
    if (t == 255) ws.bsum[blockIdx.x] = sd[255];
    if (blockIdx.x == 0 && t == 0) ws.off[0] = 0;
  }
  g.sync();

  // phase 4: block 0 exclusive-scans the 512 block sums
  if (blockIdx.x == 0) {
    __shared__ int sd2[512];
    sd2[t] = ws.bsum[t]; sd2[t + 256] = ws.bsum[t + 256];
    __syncthreads();
    if (t == 0) {
      int run = 0;
      for (int b = 0; b < 512; ++b) { int x = sd2[b]; sd2[b] = run; run += x; }
    }
    __syncthreads();
    ws.bbase[t] = sd2[t]; ws.bbase[t + 256] = sd2[t + 256];
  }
  g.sync();

  // phase 5: add block bases
  if (i3 < NNODES) ws.off[i3 + 1] += ws.bbase[blockIdx.x];
  g.sync();

  // phase 6: scatter edges into CSR
  for (int e = gtid; e < NEDGES; e += gstride) {
    int row = ei[e], col = ei[NEDGES + e];
    float wv = ws.dinv[row] * ws.dinv[col];
    int pos = ws.off[row] + atomicAdd(&ws.cursor[row], 1);
    ws.csr_col[pos] = col;
    ws.csr_w[pos]   = wv;
  }
  g.sync();

  // phase 7: Horner adjacency passes: dst = A_hat @ src + d_j * h2
  const int lane = t & 63;
  const int wid0 = blockIdx.x * 4 + (t >> 6);
  const int nwaves = 512 * 4;
  for (int j = jm - 1; j >= 0; --j) {
    const float* src = ((j + 1) & 1) ? ws.buf1 : ws.buf0;
    float*       dst = (j & 1)       ? ws.buf1 : ws.buf0;
    float dj = ws.d[j];
    for (int node = wid0; node < NNODES; node += nwaves) {
      int s = ws.off[node], e = ws.off[node + 1];
      float acc = 0.f;
      for (int base = s; base < e; base += 64) {
        int idx = base + lane;
        int cc = 0; float cw = 0.f;
        if (idx < e) { cc = ws.csr_col[idx]; cw = ws.csr_w[idx]; }
        int n = min(64, e - base);
        for (int u = 0; u < n; ++u) {
          int   c2 = __shfl(cc, u);
          float w2 = __shfl(cw, u);
          acc += w2 * src[(size_t)c2 * 64 + lane];
        }
      }
      dst[(size_t)node * 64 + lane] = acc + dj * ws.h2[(size_t)node * 64 + lane];
    }
    g.sync();
  }

  // phase 8: log_softmax over buf0 -> out
  for (int node = wid0; node < NNODES; node += nwaves) {
    size_t idx = (size_t)node * 64 + lane;
    float v = ws.buf0[idx];
    float m = v;
#pragma unroll
    for (int o = 32; o > 0; o >>= 1) m = fmaxf(m, __shfl_xor(m, o));
    float s = __expf(v - m);
#pragma unroll
    for (int o = 32; o > 0; o >>= 1) s += __shfl_xor(s, o);
    out[idx] = (v - m) - __logf(s);
  }
}

// ---------------- host ----------------
extern "C" void kernel_launch(void* const* d_in, const int* in_sizes, int n_in,
                              void* d_out, int out_size, void* d_ws, size_t ws_size,
                              hipStream_t stream) {
  const float* x    = (const float*)d_in[0];
  const int*   ei   = (const int*)  d_in[1];
  const float* W1   = (const float*)d_in[2];
  const float* b1   = (const float*)d_in[3];
  const float* W2   = (const float*)d_in[4];
  const float* b2   = (const float*)d_in[5];
  const float* temp = (const float*)d_in[6];
  float* out = (float*)d_out;

  char* w = (char*)d_ws;
  size_t o = 0;
  auto bump = [&](size_t bytes) { size_t r = o; o += (bytes + 255) & ~(size_t)255; return r; };
  WS ws;
  ws.d       = (float*)(w + bump(11 * 4));
  ws.jmax    = (int*)  (w + bump(4));
  ws.cnt     = (int*)  (w + bump((size_t)NNODES * 4));
  ws.off     = (int*)  (w + bump((size_t)(NNODES + 1) * 4));
  ws.cursor  = (int*)  (w + bump((size_t)NNODES * 4));
  ws.dinv    = (float*)(w + bump((size_t)NNODES * 4));
  ws.csr_col = (int*)  (w + bump((size_t)NEDGES * 4));
  ws.csr_w   = (float*)(w + bump((size_t)NEDGES * 4));
  ws.h2      = (float*)(w + bump((size_t)NNODES * 64 * 4));
  ws.buf0    = (float*)(w + bump((size_t)NNODES * 64 * 4));
  ws.buf1    = (float*)(w + bump((size_t)NNODES * 64 * 4));
  ws.w1s     = (short*)(w + bump((size_t)512 * 256 * 2));
  ws.w2s     = (short*)(w + bump((size_t)256 * 64 * 2));
  ws.bsum    = (int*)  (w + bump(512 * 4));
  ws.bbase   = (int*)  (w + bump(512 * 4));

  k_swzall<<<73, 256, 0, stream>>>(W1, W2, temp, ws);
  k_fwd<<<MBLK, 256, 0, stream>>>(x, b1, b2, ws, out);

  void* args[] = { (void*)&ei, (void*)&ws, (void*)&out };
  hipLaunchCooperativeKernel((void*)k_graph, dim3(512), dim3(256), args, 0, stream);
}